// Round 5
// baseline (387.726 us; speedup 1.0000x reference)
//
#include <hip/hip_runtime.h>

#define E_TOTAL 32768
#define F_IN 17
#define HID 64
#define NJ 768
#define NJP 1024          // padded: n' = oi*4 + f, f==3 is zero

using bf16x8 = __attribute__((ext_vector_type(8))) short;
using f32x4  = __attribute__((ext_vector_type(4))) float;

__device__ __forceinline__ unsigned short f2bf(float x){
    unsigned u = __float_as_uint(x);
    u += 0x7fffu + ((u >> 16) & 1u);          // round-to-nearest-even
    return (unsigned short)(u >> 16);
}

// Canonical GCN wave64 sum: row_shr 1/2/4/8 + row_bcast15(rows1,3) + row_bcast31(rows2,3),
// then readlane 63 -> uniform broadcast. VALU pipe only (no LDS traffic).
__device__ __forceinline__ float wave_sum(float x){
    x += __int_as_float(__builtin_amdgcn_update_dpp(0, __float_as_int(x), 0x111, 0xf, 0xf, true));
    x += __int_as_float(__builtin_amdgcn_update_dpp(0, __float_as_int(x), 0x112, 0xf, 0xf, true));
    x += __int_as_float(__builtin_amdgcn_update_dpp(0, __float_as_int(x), 0x114, 0xf, 0xf, true));
    x += __int_as_float(__builtin_amdgcn_update_dpp(0, __float_as_int(x), 0x118, 0xf, 0xf, true));
    x += __int_as_float(__builtin_amdgcn_update_dpp(0, __float_as_int(x), 0x142, 0xa, 0xf, true));
    x += __int_as_float(__builtin_amdgcn_update_dpp(0, __float_as_int(x), 0x143, 0xc, 0xf, true));
    return __int_as_float(__builtin_amdgcn_readlane(__float_as_int(x), 63));
}

// ---------------- prep: W3 (64x768) -> padded-transposed bf16 W3T' (1024x64) + b3p ----
// w3tp[(oi*4+f)*64 + k] = bf16(W3[k][oi*3+f]), f==3 -> 0 ;  b3p[oi*4+f] = b3[oi*3+f]
__global__ __launch_bounds__(256) void prep_w3(const float* __restrict__ W3,
        const float* __restrict__ b3, unsigned short* __restrict__ w3tp,
        float* __restrict__ b3p){
    int t = blockIdx.x * 256 + threadIdx.x;
    if (t < NJP * HID){
        int np = t >> 6, k = t & 63;
        int f = np & 3, oi = np >> 2;
        w3tp[t] = (f < 3) ? f2bf(W3[k * NJ + oi * 3 + f]) : (unsigned short)0;
    } else if (t < NJP * HID + NJP){
        int u = t - NJP * HID;
        int f = u & 3, oi = u >> 2;
        b3p[u] = (f < 3) ? b3[oi * 3 + f] : 0.0f;
    }
}

// ---------------- fused: VALU MLP (proven R3 path) + LDS-free TP ----------------
// TP via swapped-operand MFMA on f-padded W3T': D[row=n', col=edge] puts one oi's
// 3 freqs into acc[0..2] of a single lane -> einsum is 27 register FLOPs, no LDS,
// no cross-lane, no barriers. LDS = 2304 (sH) + 26944 (MLP) = 29248 B -> 4 blocks/CU.
__global__ __launch_bounds__(256, 4) void fused_kernel(const float* __restrict__ feat,
        const float* __restrict__ W1, const float* __restrict__ b1, const float* __restrict__ g1,
        const float* __restrict__ W2, const float* __restrict__ b2, const float* __restrict__ g2,
        const unsigned short* __restrict__ w3tp, const float* __restrict__ b3p,
        const float* __restrict__ basis, float* __restrict__ out){
    __shared__ __align__(16) char smem[29248];
    unsigned short* sH = (unsigned short*)smem;        // [16][72] h2 bf16
    char* rgn = smem + 2304;
    float* sW1 = (float*)rgn;                          // 4352 B  (17x64)
    float* sW2 = (float*)(rgn + 4352);                 // 16384 B (64x64)
    float* sC  = (float*)(rgn + 20736);                // 1024 B  (b1|g1|b2|g2)
    float* sFe = (float*)(rgn + 21760);                // 1088 B  (16x17)
    float* sH1 = (float*)(rgn + 22848);                // 4096 B  (16x64)

    int tid = threadIdx.x;
    int e0  = blockIdx.x * 16;
    int wv = tid >> 6, l = tid & 63;
    int j = l;                                 // MLP channel
    int c = l & 15, kg = l >> 4;               // MFMA lane split

    // ---- vectorized staging (float4) ----
    for (int i = tid; i < 272; i += 256) ((f32x4*)sW1)[i] = ((const f32x4*)W1)[i];
    #pragma unroll
    for (int k = 0; k < 4; ++k) ((f32x4*)sW2)[k * 256 + tid] = ((const f32x4*)W2)[k * 256 + tid];
    if (tid < 64){
        int g = tid >> 4, r = tid & 15;
        const float* src = (g == 0) ? b1 : (g == 1) ? g1 : (g == 2) ? b2 : g2;
        ((f32x4*)sC)[tid] = ((const f32x4*)src)[r];
    }
    if (tid < 68) ((f32x4*)sFe)[tid] = ((const f32x4*)(feat + (size_t)e0 * F_IN))[tid];
    __syncthreads();

    float acc[4], x[4];

    // ---- layer 1: 17 -> 64 ----
    #pragma unroll
    for (int q = 0; q < 4; ++q) acc[q] = sC[j];
    for (int k = 0; k < F_IN; ++k){
        float w = sW1[k * 64 + j];
        #pragma unroll
        for (int q = 0; q < 4; ++q) acc[q] += sFe[(wv * 4 + q) * F_IN + k] * w;
    }
    #pragma unroll
    for (int q = 0; q < 4; ++q){
        float a = acc[q];
        float sg = 1.0f / (1.0f + __expf(-a));
        x[q] = a * sg;
        float s1 = wave_sum(x[q]);
        float s2 = wave_sum(x[q] * x[q]);
        float mu  = s1 * (1.0f / 64.0f);
        float var = s2 * (1.0f / 64.0f) - mu * mu;
        float rs  = rsqrtf(var + 1e-5f);
        sH1[(wv * 4 + q) * 64 + j] = (x[q] - mu) * rs * sC[64 + j];
    }
    // wave-local LDS write->read: one wave's LDS ops are ordered, no barrier needed

    // ---- layer 2: 64 -> 64 ----
    #pragma unroll
    for (int q = 0; q < 4; ++q) acc[q] = sC[128 + j];
    for (int k4 = 0; k4 < 16; ++k4){
        float hv[4][4];
        #pragma unroll
        for (int q = 0; q < 4; ++q) *(float4*)hv[q] = *(const float4*)&sH1[(wv * 4 + q) * 64 + k4 * 4];
        #pragma unroll
        for (int kk = 0; kk < 4; ++kk){
            float w = sW2[(k4 * 4 + kk) * 64 + j];
            #pragma unroll
            for (int q = 0; q < 4; ++q) acc[q] += hv[q][kk] * w;
        }
    }
    #pragma unroll
    for (int q = 0; q < 4; ++q){
        float a = acc[q];
        float sg = 1.0f / (1.0f + __expf(-a));
        x[q] = a * sg;
        float s1 = wave_sum(x[q]);
        float s2 = wave_sum(x[q] * x[q]);
        float mu  = s1 * (1.0f / 64.0f);
        float var = s2 * (1.0f / 64.0f) - mu * mu;
        float rs  = rsqrtf(var + 1e-5f);
        sH[(wv * 4 + q) * 72 + j] = f2bf((x[q] - mu) * rs * sC[192 + j]);
    }

    // basis for this lane's einsum edge (issue loads before the barrier)
    float bs[27];
    {
        const float* bp = basis + (size_t)(e0 + c) * 27;
        #pragma unroll
        for (int z = 0; z < 27; ++z) bs[z] = bp[z];
    }
    __syncthreads();   // sH complete (cross-wave reads below)

    // ======== TP: LDS-free, barrier-free ========
    // B-operand (h): lane supplies B[k][col=c] = h[edge c][k]
    bf16x8 a0 = *(const bf16x8*)(sH + c * 72 + kg * 8);        // k [0,32)
    bf16x8 a1 = *(const bf16x8*)(sH + c * 72 + 32 + kg * 8);   // k [32,64)
    float* outE = out + (size_t)(e0 + c) * 2304;

    // wave wv covers oi = wv*64 .. wv*64+63 (tiles wv*16 .. wv*16+15)
    #pragma unroll 4
    for (int tt = 0; tt < 16; ++tt){
        int tile = wv * 16 + tt;                               // 16 n'-rows at tile*16
        const unsigned short* wr = w3tp + (size_t)(tile * 16 + c) * 64;
        bf16x8 A0 = *(const bf16x8*)(wr + kg * 8);             // A[row=c][k 0..32)
        bf16x8 A1 = *(const bf16x8*)(wr + 32 + kg * 8);        // A[row=c][k 32..64)
        f32x4 ac = {0.f, 0.f, 0.f, 0.f};
        ac = __builtin_amdgcn_mfma_f32_16x16x32_bf16(A0, a0, ac, 0, 0, 0);
        ac = __builtin_amdgcn_mfma_f32_16x16x32_bf16(A1, a1, ac, 0, 0, 0);
        // D[row = kg*4+r][col = c] -> n' = tile*16 + kg*4 + r -> oi = tile*4+kg, f = r
        int oi = tile * 4 + kg;
        f32x4 bb = *(const f32x4*)(b3p + oi * 4);
        float r0 = ac[0] + bb[0];
        float r1 = ac[1] + bb[1];
        float r2 = ac[2] + bb[2];
        float* p = outE + (oi >> 4) * 144 + (oi & 15) * 3;
        #pragma unroll
        for (int d = 0; d < 3; ++d){
            int z = d * 9;
            p[d * 48 + 0] = r0 * bs[z + 0] + r1 * bs[z + 1] + r2 * bs[z + 2];
            p[d * 48 + 1] = r0 * bs[z + 3] + r1 * bs[z + 4] + r2 * bs[z + 5];
            p[d * 48 + 2] = r0 * bs[z + 6] + r1 * bs[z + 7] + r2 * bs[z + 8];
        }
    }
}

extern "C" void kernel_launch(void* const* d_in, const int* in_sizes, int n_in,
                              void* d_out, int out_size, void* d_ws, size_t ws_size,
                              hipStream_t stream) {
    const float* feat  = (const float*)d_in[0];
    const float* basis = (const float*)d_in[1];
    const float* W1 = (const float*)d_in[2];
    const float* b1 = (const float*)d_in[3];
    const float* g1 = (const float*)d_in[4];
    const float* W2 = (const float*)d_in[5];
    const float* b2 = (const float*)d_in[6];
    const float* g2 = (const float*)d_in[7];
    const float* W3 = (const float*)d_in[8];
    const float* b3 = (const float*)d_in[9];
    float* out = (float*)d_out;

    unsigned short* w3tp = (unsigned short*)d_ws;                 // 1024*64*2 = 128 KB
    float* b3p = (float*)(w3tp + (size_t)NJP * HID);              // 4 KB

    prep_w3<<<(NJP * HID + NJP + 255) / 256, 256, 0, stream>>>(W3, b3, w3tp, b3p);
    fused_kernel<<<E_TOTAL / 16, 256, 0, stream>>>(feat, W1, b1, g1, W2, b2, g2,
                                                   w3tp, b3p, basis, out);
}